// Round 1
// baseline (138.790 us; speedup 1.0000x reference)
//
#include <hip/hip_runtime.h>

#define N_NODES 50000
#define N_EDGES 800000
#define D_FEAT  96

// Kernel 1: build CSR row_ptr from sorted COO rows via binary search.
// row_ptr[r] = lower_bound(rows, r), r in [0, N_NODES]; row_ptr[N]=E.
__global__ void build_row_ptr_kernel(const int* __restrict__ rows,
                                     int* __restrict__ row_ptr) {
    int r = blockIdx.x * blockDim.x + threadIdx.x;
    if (r > N_NODES) return;
    int lo = 0, hi = N_EDGES;
    while (lo < hi) {
        int mid = (lo + hi) >> 1;
        if (rows[mid] < r) lo = mid + 1;
        else hi = mid;
    }
    row_ptr[r] = lo;
}

// Kernel 2: one thread per (row, feature). 96 consecutive threads share a row,
// so embeds[cols[e]*96 + f] is coalesced across f; vals/cols loads are
// wave-uniform (cache broadcast). No atomics, each output written once.
__global__ __launch_bounds__(384) void spmm_csr_kernel(
    const int*   __restrict__ cols,
    const float* __restrict__ vals,
    const float* __restrict__ embeds,
    const int*   __restrict__ row_ptr,
    float*       __restrict__ out) {
    const int tid       = threadIdx.x;
    const int local_row = tid / D_FEAT;          // 0..3
    const int f         = tid - local_row * D_FEAT;
    const int r         = blockIdx.x * 4 + local_row;
    if (r >= N_NODES) return;

    int e   = row_ptr[r];
    int end = row_ptr[r + 1];
    float acc = 0.0f;
    for (; e < end; ++e) {
        int   c = cols[e];
        float v = vals[e];
        acc += v * embeds[c * D_FEAT + f];
    }
    out[r * D_FEAT + f] = acc;
}

extern "C" void kernel_launch(void* const* d_in, const int* in_sizes, int n_in,
                              void* d_out, int out_size, void* d_ws, size_t ws_size,
                              hipStream_t stream) {
    const int*   rows   = (const int*)  d_in[0];
    const int*   cols   = (const int*)  d_in[1];
    const float* vals   = (const float*)d_in[2];
    const float* embeds = (const float*)d_in[3];
    float*       out    = (float*)      d_out;

    int* row_ptr = (int*)d_ws;  // (N_NODES+1) ints = ~200 KB

    {
        int threads = 256;
        int blocks  = (N_NODES + 1 + threads - 1) / threads;
        build_row_ptr_kernel<<<blocks, threads, 0, stream>>>(rows, row_ptr);
    }
    {
        int threads = 384;                       // 4 rows x 96 feats
        int blocks  = (N_NODES + 3) / 4;         // 12500
        spmm_csr_kernel<<<blocks, threads, 0, stream>>>(cols, vals, embeds,
                                                        row_ptr, out);
    }
}

// Round 2
// 53.205 us; speedup vs baseline: 2.6086x; 2.6086x over previous
//
#include <hip/hip_runtime.h>

#define N_NODES 50000
#define N_EDGES 800000
#define D_FEAT  96
#define F4      (D_FEAT / 4)   // 24 float4 groups per row

// Kernel 1: build CSR row_ptr from sorted COO rows via binary search.
__global__ void build_row_ptr_kernel(const int* __restrict__ rows,
                                     int* __restrict__ row_ptr) {
    int r = blockIdx.x * blockDim.x + threadIdx.x;
    if (r > N_NODES) return;
    int lo = 0, hi = N_EDGES;
    while (lo < hi) {
        int mid = (lo + hi) >> 1;
        if (rows[mid] < r) lo = mid + 1;
        else hi = mid;
    }
    row_ptr[r] = lo;
}

// Kernel 2: one thread per (row, float4-feature-group). 24 threads/row,
// 16 rows per 384-thread block. Edge loop unrolled x4 with independent
// accumulators -> 4 gathers in flight per thread (latency hiding).
__global__ __launch_bounds__(384) void spmm_csr_kernel(
    const int*   __restrict__ cols,
    const float* __restrict__ vals,
    const float* __restrict__ embeds,
    const int*   __restrict__ row_ptr,
    float*       __restrict__ out) {
    const int tid       = threadIdx.x;
    const int local_row = tid / F4;              // 0..15
    const int fg        = tid - local_row * F4;  // 0..23
    const int r         = blockIdx.x * 16 + local_row;
    if (r >= N_NODES) return;

    const float4* __restrict__ emb4 = (const float4*)embeds;

    int e   = row_ptr[r];
    int end = row_ptr[r + 1];

    float4 a0 = make_float4(0.f, 0.f, 0.f, 0.f);
    float4 a1 = a0, a2 = a0, a3 = a0;

    for (; e + 3 < end; e += 4) {
        int   c0 = cols[e],     c1 = cols[e + 1];
        int   c2 = cols[e + 2], c3 = cols[e + 3];
        float v0 = vals[e],     v1 = vals[e + 1];
        float v2 = vals[e + 2], v3 = vals[e + 3];
        float4 m0 = emb4[(size_t)c0 * F4 + fg];
        float4 m1 = emb4[(size_t)c1 * F4 + fg];
        float4 m2 = emb4[(size_t)c2 * F4 + fg];
        float4 m3 = emb4[(size_t)c3 * F4 + fg];
        a0.x += v0 * m0.x; a0.y += v0 * m0.y; a0.z += v0 * m0.z; a0.w += v0 * m0.w;
        a1.x += v1 * m1.x; a1.y += v1 * m1.y; a1.z += v1 * m1.z; a1.w += v1 * m1.w;
        a2.x += v2 * m2.x; a2.y += v2 * m2.y; a2.z += v2 * m2.z; a2.w += v2 * m2.w;
        a3.x += v3 * m3.x; a3.y += v3 * m3.y; a3.z += v3 * m3.z; a3.w += v3 * m3.w;
    }
    for (; e < end; ++e) {
        int   c = cols[e];
        float v = vals[e];
        float4 m = emb4[(size_t)c * F4 + fg];
        a0.x += v * m.x; a0.y += v * m.y; a0.z += v * m.z; a0.w += v * m.w;
    }

    float4 s;
    s.x = (a0.x + a1.x) + (a2.x + a3.x);
    s.y = (a0.y + a1.y) + (a2.y + a3.y);
    s.z = (a0.z + a1.z) + (a2.z + a3.z);
    s.w = (a0.w + a1.w) + (a2.w + a3.w);
    ((float4*)out)[(size_t)r * F4 + fg] = s;
}

extern "C" void kernel_launch(void* const* d_in, const int* in_sizes, int n_in,
                              void* d_out, int out_size, void* d_ws, size_t ws_size,
                              hipStream_t stream) {
    const int*   rows   = (const int*)  d_in[0];
    const int*   cols   = (const int*)  d_in[1];
    const float* vals   = (const float*)d_in[2];
    const float* embeds = (const float*)d_in[3];
    float*       out    = (float*)      d_out;

    int* row_ptr = (int*)d_ws;  // (N_NODES+1) ints

    {
        int threads = 256;
        int blocks  = (N_NODES + 1 + threads - 1) / threads;
        build_row_ptr_kernel<<<blocks, threads, 0, stream>>>(rows, row_ptr);
    }
    {
        int threads = 384;                       // 16 rows x 24 float4-groups
        int blocks  = (N_NODES + 15) / 16;       // 3125
        spmm_csr_kernel<<<blocks, threads, 0, stream>>>(cols, vals, embeds,
                                                        row_ptr, out);
    }
}